// Round 11
// baseline (364.357 us; speedup 1.0000x reference)
//
#include <hip/hip_runtime.h>
#include <hip/hip_bf16.h>

#define NB 60000
#define NP 2000
#define NC 4000
#define EM_N 150000
#define EP_N 300000
#define EI_N 150000
#define POOL_N (EM_N + EP_N + EI_N)
#define SEG_TOT (NB + NB + NC)
#define SCAN_BLK 1024
#define NPART ((SEG_TOT + SCAN_BLK - 1) / SCAN_BLK)   // 122
#define BALL_BLKS ((NB + 127) / 128)                  // 469
#define PLYR_BLKS ((NP + 127) / 128)                  // 16
#define GEMM_BLKS (BALL_BLKS + PLYR_BLKS)             // 485
#define FILL_BLKS ((POOL_N + 255) / 256)              // 2344
#define COPY_BLKS ((NP * 128 + 255) / 256)            // 1000
#define BBALL ((NB + 3) / 4)                          // 15000
#define CTX_BLKS ((NC + 15) / 16)                     // 250

typedef __hip_bfloat16 bf16;
typedef unsigned int u32;
typedef __attribute__((ext_vector_type(8))) short s8v;
typedef __attribute__((ext_vector_type(4))) float f4v;

__device__ __forceinline__ short f2bs(float f) {
    bf16 h = __float2bfloat16(f);
    return __builtin_bit_cast(short, h);
}
__device__ __forceinline__ float bsToF(short s) {
    return __builtin_bit_cast(float, ((unsigned)(unsigned short)s) << 16);
}
__device__ __forceinline__ float loF(u32 v) { return bsToF((short)(v & 0xffff)); }
__device__ __forceinline__ float hiF(u32 v) { return bsToF((short)(v >> 16)); }
__device__ __forceinline__ u32 packbf(float a, float b) {
    return (u32)(unsigned short)f2bs(a) | ((u32)(unsigned short)f2bs(b) << 16);
}

// ---------------- hist + 6-weight transpose + player copy ----------------
__global__ void hist_wt_copy_kernel(const int* __restrict__ em, const int* __restrict__ ep,
                                    const int* __restrict__ ei, int* __restrict__ counts,
                                    const float* __restrict__ W0, const float* __restrict__ W1,
                                    const float* __restrict__ W2, const float* __restrict__ W3,
                                    const float* __restrict__ W4, const float* __restrict__ W5,
                                    ushort* __restrict__ Wt,
                                    const float* __restrict__ x_player, float* __restrict__ out) {
    if (blockIdx.x >= FILL_BLKS) {
        int t = (blockIdx.x - FILL_BLKS) * 256 + threadIdx.x;
        if (t < NP * 128) out[(size_t)(NB + NC) * 128 + t] = x_player[t];
        return;
    }
    int t = blockIdx.x * 256 + threadIdx.x;
    if (t < 6 * 16384) {
        int w = t >> 14, r = t & 16383, k = r >> 7, n = r & 127;
        const float* W = (w == 0) ? W0 : (w == 1) ? W1 : (w == 2) ? W2 : (w == 3) ? W3
                       : (w == 4) ? W4 : W5;
        int sc = (n >> 5) * 32 + ((n & 1) << 4) + ((n & 31) >> 1);
        Wt[w * 16384 + sc * 128 + k] = (unsigned short)f2bs(W[k * 128 + n]);
    }
    if (t < EM_N) atomicAdd(&counts[em[EM_N + t]], 1);
    else if (t < EM_N + EP_N) atomicAdd(&counts[NB + ep[EP_N + (t - EM_N)]], 1);
    else if (t < POOL_N) atomicAdd(&counts[2 * NB + ei[EI_N + (t - EM_N - EP_N)]], 1);
}

// ---------------- fused scan: block-local scan + atomic base ----------------
__global__ void scan_fused_kernel(const int* __restrict__ counts, int* __restrict__ offsets,
                                  int* __restrict__ cursors, int* __restrict__ gbase) {
    __shared__ int sd[256];
    __shared__ int sbase;
    int b = blockIdx.x, tid = threadIdx.x;
    int base = b * SCAN_BLK + tid * 4;
    int v[4]; int ts = 0;
#pragma unroll
    for (int j = 0; j < 4; j++) { int idx = base + j; v[j] = (idx < SEG_TOT) ? counts[idx] : 0; ts += v[j]; }
    sd[tid] = ts;
    for (int off = 1; off < 256; off <<= 1) {
        __syncthreads(); int t = (tid >= off) ? sd[tid - off] : 0;
        __syncthreads(); sd[tid] += t;
    }
    __syncthreads();
    if (tid == 255) sbase = atomicAdd(gbase, sd[255]);
    __syncthreads();
    int run = sd[tid] - ts + sbase;
#pragma unroll
    for (int j = 0; j < 4; j++) {
        int idx = base + j;
        if (idx < SEG_TOT) { offsets[idx] = run; cursors[idx] = run; }
        run += v[j];
    }
}

// ---------------- merged: MFMA 6-matrix GEMM blocks + pool-fill blocks ----------------
// skipP gets residual folded: skipP = bf16(x@Wskip + bskip + x_ball + g_b)
__global__ __launch_bounds__(256) void gemm6_fill_kernel(
    const float* __restrict__ Aball, const float* __restrict__ Aplyr,
    const ushort* __restrict__ Wt,
    const float* __restrict__ bq, const float* __restrict__ bk,
    const float* __restrict__ bv_, const float* __restrict__ bskip,
    const float* __restrict__ g_b,
    u32* __restrict__ xrP, u32* __restrict__ qP, u32* __restrict__ kvP,
    u32* __restrict__ skipP, u32* __restrict__ xlP,
    const int* __restrict__ em, const int* __restrict__ ep, const int* __restrict__ ei,
    const float* __restrict__ ea_p, int* __restrict__ cursors, int2* __restrict__ pool) {
    if (blockIdx.x >= GEMM_BLKS) {
        int t = (blockIdx.x - GEMM_BLKS) * 256 + threadIdx.x;
        int seg, s; float ea = 0.f;
        if (t < EM_N) { s = em[t]; seg = em[EM_N + t]; }
        else if (t < EM_N + EP_N) { int e = t - EM_N; s = ep[e]; seg = NB + ep[EP_N + e]; ea = ea_p[e]; }
        else if (t < POOL_N) { int e = t - EM_N - EP_N; s = ei[e]; seg = 2 * NB + ei[EI_N + e]; }
        else return;
        int pos = atomicAdd(&cursors[seg], 1);
        pool[pos] = make_int2(s, __float_as_int(ea));
        return;
    }
    const int lane = threadIdx.x & 63;
    const int wv = threadIdx.x >> 6;
    const int quad = lane >> 4, l16 = lane & 15;
    const bool plyr = (blockIdx.x >= BALL_BLKS);
    const int M = plyr ? NP : NB;
    const float* A = plyr ? Aplyr : Aball;
    const int mbase = (plyr ? (blockIdx.x - BALL_BLKS) : blockIdx.x) * 128 + wv * 32;

    s8v a[2][4];
#pragma unroll
    for (int mt = 0; mt < 2; mt++) {
        int row = mbase + mt * 16 + l16;
        if (row >= M) row = M - 1;
        const float* ap = A + (size_t)row * 128 + quad * 8;
#pragma unroll
        for (int kt = 0; kt < 4; kt++) {
            const float4* p = (const float4*)(ap + kt * 32);
            float4 u = p[0], v = p[1];
            s8v f;
            f[0] = f2bs(u.x); f[1] = f2bs(u.y); f[2] = f2bs(u.z); f[3] = f2bs(u.w);
            f[4] = f2bs(v.x); f[5] = f2bs(v.y); f[6] = f2bs(v.z); f[7] = f2bs(v.w);
            a[mt][kt] = f;
        }
    }

    const int wbeg = plyr ? 5 : 0, wend = plyr ? 6 : 5;
    for (int w = wbeg; w < wend; w++) {
        const ushort* wt = Wt + w * 16384;
        u32* op; const float* bp; int stride, obase;
        if (w == 0)      { op = xrP;   bp = nullptr; stride = 64;  obase = 0; }
        else if (w == 1) { op = qP;    bp = bq;      stride = 64;  obase = 0; }
        else if (w == 2) { op = kvP;   bp = bk;      stride = 128; obase = 0; }
        else if (w == 3) { op = kvP;   bp = bv_;     stride = 128; obase = 1; }
        else if (w == 4) { op = skipP; bp = bskip;   stride = 64;  obase = 0; }
        else             { op = xlP;   bp = nullptr; stride = 64;  obase = 0; }
        const int kvmul = (stride == 128) ? 2 : 1;
        const bool resid = (w == 4);
#pragma unroll
        for (int t = 0; t < 4; t++) {
            s8v blo[4], bhi[4];
#pragma unroll
            for (int kt = 0; kt < 4; kt++) {
                blo[kt] = *(const s8v*)(wt + (t * 32 + l16) * 128 + kt * 32 + quad * 8);
                bhi[kt] = *(const s8v*)(wt + (t * 32 + 16 + l16) * 128 + kt * 32 + quad * 8);
            }
            float bvlo = 0.f, bvhi = 0.f;
            if (bp) { float2 b2 = ((const float2*)bp)[t * 16 + l16]; bvlo = b2.x; bvhi = b2.y; }
            if (resid) { float2 gb2 = ((const float2*)g_b)[t * 16 + l16]; bvlo += gb2.x; bvhi += gb2.y; }
#pragma unroll
            for (int mt = 0; mt < 2; mt++) {
                f4v alo = {0.f, 0.f, 0.f, 0.f}, ahi = {0.f, 0.f, 0.f, 0.f};
#pragma unroll
                for (int kt = 0; kt < 4; kt++) {
                    alo = __builtin_amdgcn_mfma_f32_16x16x32_bf16(a[mt][kt], blo[kt], alo, 0, 0, 0);
                    ahi = __builtin_amdgcn_mfma_f32_16x16x32_bf16(a[mt][kt], bhi[kt], ahi, 0, 0, 0);
                }
#pragma unroll
                for (int r = 0; r < 4; r++) {
                    int row = mbase + mt * 16 + quad * 4 + r;
                    if (row < M) {
                        float vlo = alo[r] + bvlo, vhi = ahi[r] + bvhi;
                        if (resid) {
                            float2 xr2 = ((const float2*)Aball)[(size_t)row * 64 + t * 16 + l16];
                            vlo += xr2.x; vhi += xr2.y;
                        }
                        op[(size_t)row * stride + (t * 16 + l16) * kvmul + obase] = packbf(vlo, vhi);
                    }
                }
            }
        }
    }
}

// ---------------- merged: ball (GAT+TR+skip+LN) | ctx (inline sage + GEMM + LN) ----------------
__global__ __launch_bounds__(256) void ball_ctx_kernel(
    const u32* __restrict__ xlP, const u32* __restrict__ xrP, const u32* __restrict__ qP,
    const u32* __restrict__ kvP, const u32* __restrict__ skipP,
    const float* __restrict__ x_ball, const float* __restrict__ xc,
    const float* __restrict__ g_att, const float* __restrict__ We,
    const int* __restrict__ offsets, const int* __restrict__ counts,
    const int2* __restrict__ pool,
    const float* __restrict__ ln_g, const float* __restrict__ ln_b,
    const float* __restrict__ Wr, const float* __restrict__ Wl, const float* __restrict__ bl,
    const float* __restrict__ cg, const float* __restrict__ cb,
    float* __restrict__ out) {
    __shared__ float A0[16 * 128];
    __shared__ float CB[16 * 128];   // holds A1 (sage mean) during k-loop, then output tile
    const int wv = threadIdx.x >> 6, l = threadIdx.x & 63;

    if (blockIdx.x >= BBALL) {
        // ======== ctx path: inline sage gather -> 2-input GEMM + residual + LN ========
        const int tid = threadIdx.x;
        const int row0 = (blockIdx.x - BBALL) * 16;
        for (int i = tid; i < 16 * 128; i += 256) {
            int r = row0 + (i >> 7);
            A0[i] = (r < NC) ? xc[(size_t)r * 128 + (i & 127)] : 0.f;
        }
        // sage: wave wv handles local nodes wv*4+rr
        for (int rr = 0; rr < 4; rr++) {
            int n = wv * 4 + rr, c = row0 + n;
            float s0 = 0.f, s1 = 0.f; int cnt = 0;
            if (c < NC) {
                int beg = offsets[2 * NB + c]; cnt = counts[2 * NB + c];
                int j = 0;
                for (; j + 1 < cnt; j += 2) {
                    int sA = pool[beg + j].x, sB = pool[beg + j + 1].x;
                    float2 xa = ((const float2*)x_ball)[(size_t)sA * 64 + l];
                    float2 xb = ((const float2*)x_ball)[(size_t)sB * 64 + l];
                    s0 += xa.x + xb.x; s1 += xa.y + xb.y;
                }
                if (j < cnt) {
                    float2 xv = ((const float2*)x_ball)[(size_t)pool[beg + j].x * 64 + l];
                    s0 += xv.x; s1 += xv.y;
                }
            }
            float m = fmaxf((float)cnt, 1.f);
            CB[n * 128 + 2 * l] = s0 / m;
            CB[n * 128 + 2 * l + 1] = s1 / m;
        }
        __syncthreads();
        const int col = tid & 127, rg = tid >> 7;
        float acc[8];
#pragma unroll
        for (int i = 0; i < 8; i++) acc[i] = 0.f;
        for (int k = 0; k < 128; k++) {
            float w0 = Wr[k * 128 + col], w1 = Wl[k * 128 + col];
#pragma unroll
            for (int i = 0; i < 8; i++)
                acc[i] += A0[(rg * 8 + i) * 128 + k] * w0 + CB[(rg * 8 + i) * 128 + k] * w1;
        }
        float bv = bl[col];
        __syncthreads();   // all reads of CB-as-A1 done before overwrite
#pragma unroll
        for (int i = 0; i < 8; i++)
            CB[(rg * 8 + i) * 128 + col] = acc[i] + bv + A0[(rg * 8 + i) * 128 + col];
        __syncthreads();
        for (int r = 0; r < 4; r++) {
            int lr = wv * 4 + r, row = row0 + lr;
            if (row >= NC) break;
            float v0 = CB[lr * 128 + l], v1 = CB[lr * 128 + l + 64];
            float s = v0 + v1;
#pragma unroll
            for (int m = 1; m <= 32; m <<= 1) s += __shfl_xor(s, m);
            float mu = s * (1.f / 128.f);
            float d0 = v0 - mu, d1 = v1 - mu;
            float qv = d0 * d0 + d1 * d1;
#pragma unroll
            for (int m = 1; m <= 32; m <<= 1) qv += __shfl_xor(qv, m);
            float inv = rsqrtf(qv * (1.f / 128.f) + 1e-5f);
            out[(size_t)(NB + row) * 128 + l] = d0 * inv * cg[l] + cb[l];
            out[(size_t)(NB + row) * 128 + l + 64] = d1 * inv * cg[l + 64] + cb[l + 64];
        }
        return;
    }

    // ======== ball path: one wave per node, pairing (2l,2l+1), head = l>>4 ========
    const int d = blockIdx.x * 4 + wv;
    if (d >= NB) return;
    const size_t rowD = (size_t)d * 64;

    // ---- GATv2 (player -> ball), 4-edge pipeline ----
    float2 att = ((const float2*)g_att)[l];
    u32 xr2 = xrP[rowD + l];
    float xr0 = loF(xr2), xr1 = hiF(xr2);
    int beg = offsets[d], cnt = counts[d];
    float n0 = 0.f, n1 = 0.f, deg = 0.f;
    int j = 0;
    for (; j + 3 < cnt; j += 4) {
        int s0 = pool[beg + j].x, s1 = pool[beg + j + 1].x;
        int s2 = pool[beg + j + 2].x, s3 = pool[beg + j + 3].x;
        u32 xv[4] = {xlP[(size_t)s0 * 64 + l], xlP[(size_t)s1 * 64 + l],
                     xlP[(size_t)s2 * 64 + l], xlP[(size_t)s3 * 64 + l]};
        float p[4], xa[4], xb[4];
#pragma unroll
        for (int i = 0; i < 4; i++) {
            xa[i] = loF(xv[i]); xb[i] = hiF(xv[i]);
            float u0 = xa[i] + xr0; u0 = u0 > 0.f ? u0 : 0.2f * u0;
            float u1 = xb[i] + xr1; u1 = u1 > 0.f ? u1 : 0.2f * u1;
            p[i] = u0 * att.x + u1 * att.y;
        }
#pragma unroll
        for (int m = 1; m <= 8; m <<= 1) {
#pragma unroll
            for (int i = 0; i < 4; i++) p[i] += __shfl_xor(p[i], m);
        }
#pragma unroll
        for (int i = 0; i < 4; i++) {
            p[i] = __expf(p[i]);
            n0 += p[i] * xa[i]; n1 += p[i] * xb[i]; deg += p[i];
        }
    }
    for (; j < cnt; j++) {
        int s = pool[beg + j].x;
        u32 xv = xlP[(size_t)s * 64 + l];
        float x0 = loF(xv), x1 = hiF(xv);
        float u0 = x0 + xr0; u0 = u0 > 0.f ? u0 : 0.2f * u0;
        float u1 = x1 + xr1; u1 = u1 > 0.f ? u1 : 0.2f * u1;
        float p = u0 * att.x + u1 * att.y;
#pragma unroll
        for (int m = 1; m <= 8; m <<= 1) p += __shfl_xor(p, m);
        p = __expf(p);
        n0 += p * x0; n1 += p * x1; deg += p;
    }
    float gat0 = n0 / (deg + 1e-16f), gat1 = n1 / (deg + 1e-16f);

    // ---- TransformerConv (ball -> ball), 4-edge pipeline ----
    u32 q2 = qP[rowD + l];
    float q0 = loF(q2), q1 = hiF(q2);
    float2 we = ((const float2*)We)[l];
    float dw = q0 * we.x + q1 * we.y;
#pragma unroll
    for (int m = 1; m <= 8; m <<= 1) dw += __shfl_xor(dw, m);
    beg = offsets[NB + d]; cnt = counts[NB + d];
    float sv0 = 0.f, sv1 = 0.f, spe = 0.f, det = 0.f;
    const uint2* kv2p = (const uint2*)kvP;
    j = 0;
    for (; j + 3 < cnt; j += 4) {
        int2 pr[4] = {pool[beg + j], pool[beg + j + 1], pool[beg + j + 2], pool[beg + j + 3]};
        uint2 kv[4];
#pragma unroll
        for (int i = 0; i < 4; i++) kv[i] = kv2p[(size_t)pr[i].x * 64 + l];
        float p[4], ea[4];
#pragma unroll
        for (int i = 0; i < 4; i++) {
            ea[i] = __int_as_float(pr[i].y);
            p[i] = q0 * loF(kv[i].x) + q1 * hiF(kv[i].x);
        }
#pragma unroll
        for (int m = 1; m <= 8; m <<= 1) {
#pragma unroll
            for (int i = 0; i < 4; i++) p[i] += __shfl_xor(p[i], m);
        }
#pragma unroll
        for (int i = 0; i < 4; i++) {
            p[i] = __expf((p[i] + ea[i] * dw) * 0.17677669529663687f);
            sv0 += p[i] * loF(kv[i].y); sv1 += p[i] * hiF(kv[i].y);
            spe += p[i] * ea[i]; det += p[i];
        }
    }
    for (; j < cnt; j++) {
        int2 pr = pool[beg + j];
        float ea = __int_as_float(pr.y);
        uint2 kv = kv2p[(size_t)pr.x * 64 + l];
        float p = q0 * loF(kv.x) + q1 * hiF(kv.x);
#pragma unroll
        for (int m = 1; m <= 8; m <<= 1) p += __shfl_xor(p, m);
        p = __expf((p + ea * dw) * 0.17677669529663687f);
        sv0 += p * loF(kv.y); sv1 += p * hiF(kv.y);
        spe += p * ea; det += p;
    }
    float tr0 = (sv0 + spe * we.x) / (det + 1e-16f);
    float tr1 = (sv1 + spe * we.y) / (det + 1e-16f);

    // ---- residual(pre-folded in skipP) + LayerNorm ----
    u32 sk = skipP[rowD + l];
    float val0 = loF(sk) + gat0 + tr0;
    float val1 = hiF(sk) + gat1 + tr1;
    float s = val0 + val1;
#pragma unroll
    for (int m = 1; m <= 32; m <<= 1) s += __shfl_xor(s, m);
    float mu = s * (1.f / 128.f);
    float d0 = val0 - mu, d1 = val1 - mu;
    float qv = d0 * d0 + d1 * d1;
#pragma unroll
    for (int m = 1; m <= 32; m <<= 1) qv += __shfl_xor(qv, m);
    float inv = rsqrtf(qv * (1.f / 128.f) + 1e-5f);
    float2 g2 = ((const float2*)ln_g)[l];
    float2 b2 = ((const float2*)ln_b)[l];
    ((float2*)out)[rowD + l] = make_float2(d0 * inv * g2.x + b2.x, d1 * inv * g2.y + b2.y);
}

extern "C" void kernel_launch(void* const* d_in, const int* in_sizes, int n_in,
                              void* d_out, int out_size, void* d_ws, size_t ws_size,
                              hipStream_t stream) {
    const float* x_ball = (const float*)d_in[0];
    const float* x_player = (const float*)d_in[1];
    const float* x_context = (const float*)d_in[2];
    const int* em = (const int*)d_in[3];
    const int* ep = (const int*)d_in[4];
    const int* ei = (const int*)d_in[5];
    const float* ea_p = (const float*)d_in[6];
    const float* g_Wl = (const float*)d_in[7];
    const float* g_Wr = (const float*)d_in[8];
    const float* g_att = (const float*)d_in[9];
    const float* g_b = (const float*)d_in[10];
    const float* t_Wq = (const float*)d_in[11];
    const float* t_bq = (const float*)d_in[12];
    const float* t_Wk = (const float*)d_in[13];
    const float* t_bk = (const float*)d_in[14];
    const float* t_Wv = (const float*)d_in[15];
    const float* t_bv = (const float*)d_in[16];
    const float* t_We = (const float*)d_in[17];
    const float* t_Wskip = (const float*)d_in[18];
    const float* t_bskip = (const float*)d_in[19];
    const float* s_Wl = (const float*)d_in[20];
    const float* s_bl = (const float*)d_in[21];
    const float* s_Wr = (const float*)d_in[22];
    const float* ln_ball_g = (const float*)d_in[23];
    const float* ln_ball_b = (const float*)d_in[24];
    const float* ln_ctx_g = (const float*)d_in[25];
    const float* ln_ctx_b = (const float*)d_in[26];
    float* out = (float*)d_out;

    // ---- workspace (~85 MB) ----
    float* ws = (float*)d_ws;
    size_t o = 0;
    int* counts = (int*)(ws + o);   o += SEG_TOT;
    int* gbase = (int*)(ws + o);    o += 1;     // zeroed with counts
    int* offsets = (int*)(ws + o);  o += SEG_TOT;
    int* cursors = (int*)(ws + o);  o += SEG_TOT;
    if (o & 1) o++;
    int2* pool = (int2*)(ws + o);   o += (size_t)POOL_N * 2;
    ushort* Wt = (ushort*)(ws + o); o += (6 * 16384) / 2;
    u32* xlP = (u32*)(ws + o);      o += (size_t)NP * 64;
    u32* xrP = (u32*)(ws + o);      o += (size_t)NB * 64;
    u32* qP = (u32*)(ws + o);       o += (size_t)NB * 64;
    u32* skipP = (u32*)(ws + o);    o += (size_t)NB * 64;
    if (o & 1) o++;
    u32* kvP = (u32*)(ws + o);      o += (size_t)NB * 128;

    dim3 blk(256);
    hipMemsetAsync(counts, 0, (SEG_TOT + 1) * sizeof(int), stream);
    hist_wt_copy_kernel<<<FILL_BLKS + COPY_BLKS, blk, 0, stream>>>(
        em, ep, ei, counts, g_Wr, t_Wq, t_Wk, t_Wv, t_Wskip, g_Wl, Wt, x_player, out);
    scan_fused_kernel<<<NPART, blk, 0, stream>>>(counts, offsets, cursors, gbase);
    gemm6_fill_kernel<<<GEMM_BLKS + FILL_BLKS, blk, 0, stream>>>(
        x_ball, x_player, Wt, t_bq, t_bk, t_bv, t_bskip, g_b,
        xrP, qP, kvP, skipP, xlP, em, ep, ei, ea_p, cursors, pool);
    ball_ctx_kernel<<<BBALL + CTX_BLKS, blk, 0, stream>>>(
        xlP, xrP, qP, kvP, skipP, x_ball, x_context, g_att, t_We,
        offsets, counts, pool, ln_ball_g, ln_ball_b,
        s_Wr, s_Wl, s_bl, ln_ctx_g, ln_ctx_b, out);
}

// Round 12
// 334.441 us; speedup vs baseline: 1.0895x; 1.0895x over previous
//
#include <hip/hip_runtime.h>
#include <hip/hip_bf16.h>

#define NB 60000
#define NP 2000
#define NC 4000
#define EM_N 150000
#define EP_N 300000
#define EI_N 150000
#define POOL_N (EM_N + EP_N + EI_N)
#define SEG_TOT (NB + NB + NC)
#define SCAN_BLK 1024
#define NPART ((SEG_TOT + SCAN_BLK - 1) / SCAN_BLK)   // 122
#define BALL_BLKS ((NB + 127) / 128)                  // 469
#define PLYR_BLKS ((NP + 127) / 128)                  // 16
#define GEMM_BLKS (BALL_BLKS + PLYR_BLKS)             // 485
#define FILL_BLKS ((POOL_N + 255) / 256)              // 2344
#define COPY_BLKS ((NP * 128 + 255) / 256)            // 1000
#define BBALL ((NB + 3) / 4)                          // 15000
#define CTX_BLKS ((NC + 15) / 16)                     // 250

typedef __hip_bfloat16 bf16;
typedef unsigned int u32;
typedef __attribute__((ext_vector_type(8))) short s8v;
typedef __attribute__((ext_vector_type(4))) float f4v;

__device__ __forceinline__ short f2bs(float f) {
    bf16 h = __float2bfloat16(f);
    return __builtin_bit_cast(short, h);
}
__device__ __forceinline__ float bsToF(short s) {
    return __builtin_bit_cast(float, ((unsigned)(unsigned short)s) << 16);
}
__device__ __forceinline__ float loF(u32 v) { return bsToF((short)(v & 0xffff)); }
__device__ __forceinline__ float hiF(u32 v) { return bsToF((short)(v >> 16)); }
__device__ __forceinline__ u32 packbf(float a, float b) {
    return (u32)(unsigned short)f2bs(a) | ((u32)(unsigned short)f2bs(b) << 16);
}

// ---------------- hist + 6-weight transpose + player copy ----------------
__global__ void hist_wt_copy_kernel(const int* __restrict__ em, const int* __restrict__ ep,
                                    const int* __restrict__ ei, int* __restrict__ counts,
                                    const float* __restrict__ W0, const float* __restrict__ W1,
                                    const float* __restrict__ W2, const float* __restrict__ W3,
                                    const float* __restrict__ W4, const float* __restrict__ W5,
                                    ushort* __restrict__ Wt,
                                    const float* __restrict__ x_player, float* __restrict__ out) {
    if (blockIdx.x >= FILL_BLKS) {
        int t = (blockIdx.x - FILL_BLKS) * 256 + threadIdx.x;
        if (t < NP * 128) out[(size_t)(NB + NC) * 128 + t] = x_player[t];
        return;
    }
    int t = blockIdx.x * 256 + threadIdx.x;
    if (t < 6 * 16384) {
        int w = t >> 14, r = t & 16383, k = r >> 7, n = r & 127;
        const float* W = (w == 0) ? W0 : (w == 1) ? W1 : (w == 2) ? W2 : (w == 3) ? W3
                       : (w == 4) ? W4 : W5;
        int sc = (n >> 5) * 32 + ((n & 1) << 4) + ((n & 31) >> 1);
        Wt[w * 16384 + sc * 128 + k] = (unsigned short)f2bs(W[k * 128 + n]);
    }
    if (t < EM_N) atomicAdd(&counts[em[EM_N + t]], 1);
    else if (t < EM_N + EP_N) atomicAdd(&counts[NB + ep[EP_N + (t - EM_N)]], 1);
    else if (t < POOL_N) atomicAdd(&counts[2 * NB + ei[EI_N + (t - EM_N - EP_N)]], 1);
}

// ---------------- fused scan: block-local scan + atomic base ----------------
__global__ void scan_fused_kernel(const int* __restrict__ counts, int* __restrict__ offsets,
                                  int* __restrict__ cursors, int* __restrict__ gbase) {
    __shared__ int sd[256];
    __shared__ int sbase;
    int b = blockIdx.x, tid = threadIdx.x;
    int base = b * SCAN_BLK + tid * 4;
    int v[4]; int ts = 0;
#pragma unroll
    for (int j = 0; j < 4; j++) { int idx = base + j; v[j] = (idx < SEG_TOT) ? counts[idx] : 0; ts += v[j]; }
    sd[tid] = ts;
    for (int off = 1; off < 256; off <<= 1) {
        __syncthreads(); int t = (tid >= off) ? sd[tid - off] : 0;
        __syncthreads(); sd[tid] += t;
    }
    __syncthreads();
    if (tid == 255) sbase = atomicAdd(gbase, sd[255]);
    __syncthreads();
    int run = sd[tid] - ts + sbase;
#pragma unroll
    for (int j = 0; j < 4; j++) {
        int idx = base + j;
        if (idx < SEG_TOT) { offsets[idx] = run; cursors[idx] = run; }
        run += v[j];
    }
}

// ---------------- merged: MFMA 6-matrix GEMM blocks + pool-fill blocks ----------------
// skipP gets residual folded: skipP = bf16(x@Wskip + bskip + x_ball + g_b)
__global__ __launch_bounds__(256) void gemm6_fill_kernel(
    const float* __restrict__ Aball, const float* __restrict__ Aplyr,
    const ushort* __restrict__ Wt,
    const float* __restrict__ bq, const float* __restrict__ bk,
    const float* __restrict__ bv_, const float* __restrict__ bskip,
    const float* __restrict__ g_b,
    u32* __restrict__ xrP, u32* __restrict__ qP, u32* __restrict__ kvP,
    u32* __restrict__ skipP, u32* __restrict__ xlP,
    const int* __restrict__ em, const int* __restrict__ ep, const int* __restrict__ ei,
    const float* __restrict__ ea_p, int* __restrict__ cursors, int2* __restrict__ pool) {
    if (blockIdx.x >= GEMM_BLKS) {
        int t = (blockIdx.x - GEMM_BLKS) * 256 + threadIdx.x;
        int seg, s; float ea = 0.f;
        if (t < EM_N) { s = em[t]; seg = em[EM_N + t]; }
        else if (t < EM_N + EP_N) { int e = t - EM_N; s = ep[e]; seg = NB + ep[EP_N + e]; ea = ea_p[e]; }
        else if (t < POOL_N) { int e = t - EM_N - EP_N; s = ei[e]; seg = 2 * NB + ei[EI_N + e]; }
        else return;
        int pos = atomicAdd(&cursors[seg], 1);
        pool[pos] = make_int2(s, __float_as_int(ea));
        return;
    }
    const int lane = threadIdx.x & 63;
    const int wv = threadIdx.x >> 6;
    const int quad = lane >> 4, l16 = lane & 15;
    const bool plyr = (blockIdx.x >= BALL_BLKS);
    const int M = plyr ? NP : NB;
    const float* A = plyr ? Aplyr : Aball;
    const int mbase = (plyr ? (blockIdx.x - BALL_BLKS) : blockIdx.x) * 128 + wv * 32;

    s8v a[2][4];
#pragma unroll
    for (int mt = 0; mt < 2; mt++) {
        int row = mbase + mt * 16 + l16;
        if (row >= M) row = M - 1;
        const float* ap = A + (size_t)row * 128 + quad * 8;
#pragma unroll
        for (int kt = 0; kt < 4; kt++) {
            const float4* p = (const float4*)(ap + kt * 32);
            float4 u = p[0], v = p[1];
            s8v f;
            f[0] = f2bs(u.x); f[1] = f2bs(u.y); f[2] = f2bs(u.z); f[3] = f2bs(u.w);
            f[4] = f2bs(v.x); f[5] = f2bs(v.y); f[6] = f2bs(v.z); f[7] = f2bs(v.w);
            a[mt][kt] = f;
        }
    }

    const int wbeg = plyr ? 5 : 0, wend = plyr ? 6 : 5;
    for (int w = wbeg; w < wend; w++) {
        const ushort* wt = Wt + w * 16384;
        u32* op; const float* bp; int stride, obase;
        if (w == 0)      { op = xrP;   bp = nullptr; stride = 64;  obase = 0; }
        else if (w == 1) { op = qP;    bp = bq;      stride = 64;  obase = 0; }
        else if (w == 2) { op = kvP;   bp = bk;      stride = 128; obase = 0; }
        else if (w == 3) { op = kvP;   bp = bv_;     stride = 128; obase = 1; }
        else if (w == 4) { op = skipP; bp = bskip;   stride = 64;  obase = 0; }
        else             { op = xlP;   bp = nullptr; stride = 64;  obase = 0; }
        const int kvmul = (stride == 128) ? 2 : 1;
        const bool resid = (w == 4);
#pragma unroll
        for (int t = 0; t < 4; t++) {
            s8v blo[4], bhi[4];
#pragma unroll
            for (int kt = 0; kt < 4; kt++) {
                blo[kt] = *(const s8v*)(wt + (t * 32 + l16) * 128 + kt * 32 + quad * 8);
                bhi[kt] = *(const s8v*)(wt + (t * 32 + 16 + l16) * 128 + kt * 32 + quad * 8);
            }
            float bvlo = 0.f, bvhi = 0.f;
            if (bp) { float2 b2 = ((const float2*)bp)[t * 16 + l16]; bvlo = b2.x; bvhi = b2.y; }
            if (resid) { float2 gb2 = ((const float2*)g_b)[t * 16 + l16]; bvlo += gb2.x; bvhi += gb2.y; }
#pragma unroll
            for (int mt = 0; mt < 2; mt++) {
                f4v alo = {0.f, 0.f, 0.f, 0.f}, ahi = {0.f, 0.f, 0.f, 0.f};
#pragma unroll
                for (int kt = 0; kt < 4; kt++) {
                    alo = __builtin_amdgcn_mfma_f32_16x16x32_bf16(a[mt][kt], blo[kt], alo, 0, 0, 0);
                    ahi = __builtin_amdgcn_mfma_f32_16x16x32_bf16(a[mt][kt], bhi[kt], ahi, 0, 0, 0);
                }
#pragma unroll
                for (int r = 0; r < 4; r++) {
                    int row = mbase + mt * 16 + quad * 4 + r;
                    if (row < M) {
                        float vlo = alo[r] + bvlo, vhi = ahi[r] + bvhi;
                        if (resid) {
                            float2 xr2 = ((const float2*)Aball)[(size_t)row * 64 + t * 16 + l16];
                            vlo += xr2.x; vhi += xr2.y;
                        }
                        op[(size_t)row * stride + (t * 16 + l16) * kvmul + obase] = packbf(vlo, vhi);
                    }
                }
            }
        }
    }
}

// ---------------- merged: ball (GAT+TR+skip+LN) | sage gather  (2 KB LDS only) ----------------
__global__ __launch_bounds__(256) void ball_sage_kernel(
    const u32* __restrict__ xlP, const u32* __restrict__ xrP, const u32* __restrict__ qP,
    const u32* __restrict__ kvP, const u32* __restrict__ skipP,
    const float* __restrict__ x_ball,
    const float* __restrict__ g_att, const float* __restrict__ We,
    const int* __restrict__ offsets, const int* __restrict__ counts,
    const int2* __restrict__ pool,
    const float* __restrict__ ln_g, const float* __restrict__ ln_b,
    float* __restrict__ summ, float* __restrict__ out) {
    __shared__ float part[4][128];
    const int wv = threadIdx.x >> 6, l = threadIdx.x & 63;

    if (blockIdx.x >= BBALL) {
        // ---- SAGE gather (4-way edge split per ctx node) ----
        int c = blockIdx.x - BBALL;
        int beg = offsets[2 * NB + c], cnt = counts[2 * NB + c];
        float s0 = 0.f, s1 = 0.f;
        for (int j = wv; j < cnt; j += 4) {
            int s = pool[beg + j].x;
            float2 xv = ((const float2*)x_ball)[(size_t)s * 64 + l];
            s0 += xv.x; s1 += xv.y;
        }
        part[wv][l * 2] = s0; part[wv][l * 2 + 1] = s1;
        __syncthreads();
        if (wv == 0) {
            float m = fmaxf((float)cnt, 1.f);
            size_t rowC = (size_t)c * 128;
            summ[rowC + l * 2] = (part[0][l * 2] + part[1][l * 2] + part[2][l * 2] + part[3][l * 2]) / m;
            summ[rowC + l * 2 + 1] =
                (part[0][l * 2 + 1] + part[1][l * 2 + 1] + part[2][l * 2 + 1] + part[3][l * 2 + 1]) / m;
        }
        return;
    }

    // ---- ball path: one wave per node, pairing (2l,2l+1), head = l>>4 ----
    const int d = blockIdx.x * 4 + wv;
    if (d >= NB) return;
    const size_t rowD = (size_t)d * 64;

    // ======== GATv2 (player -> ball), 4-edge pipeline ========
    float2 att = ((const float2*)g_att)[l];
    u32 xr2 = xrP[rowD + l];
    float xr0 = loF(xr2), xr1 = hiF(xr2);
    int beg = offsets[d], cnt = counts[d];
    float n0 = 0.f, n1 = 0.f, deg = 0.f;
    int j = 0;
    for (; j + 3 < cnt; j += 4) {
        int s0 = pool[beg + j].x, s1 = pool[beg + j + 1].x;
        int s2 = pool[beg + j + 2].x, s3 = pool[beg + j + 3].x;
        u32 xv[4] = {xlP[(size_t)s0 * 64 + l], xlP[(size_t)s1 * 64 + l],
                     xlP[(size_t)s2 * 64 + l], xlP[(size_t)s3 * 64 + l]};
        float p[4], xa[4], xb[4];
#pragma unroll
        for (int i = 0; i < 4; i++) {
            xa[i] = loF(xv[i]); xb[i] = hiF(xv[i]);
            float u0 = xa[i] + xr0; u0 = u0 > 0.f ? u0 : 0.2f * u0;
            float u1 = xb[i] + xr1; u1 = u1 > 0.f ? u1 : 0.2f * u1;
            p[i] = u0 * att.x + u1 * att.y;
        }
#pragma unroll
        for (int m = 1; m <= 8; m <<= 1) {
#pragma unroll
            for (int i = 0; i < 4; i++) p[i] += __shfl_xor(p[i], m);
        }
#pragma unroll
        for (int i = 0; i < 4; i++) {
            p[i] = __expf(p[i]);
            n0 += p[i] * xa[i]; n1 += p[i] * xb[i]; deg += p[i];
        }
    }
    for (; j < cnt; j++) {
        int s = pool[beg + j].x;
        u32 xv = xlP[(size_t)s * 64 + l];
        float x0 = loF(xv), x1 = hiF(xv);
        float u0 = x0 + xr0; u0 = u0 > 0.f ? u0 : 0.2f * u0;
        float u1 = x1 + xr1; u1 = u1 > 0.f ? u1 : 0.2f * u1;
        float p = u0 * att.x + u1 * att.y;
#pragma unroll
        for (int m = 1; m <= 8; m <<= 1) p += __shfl_xor(p, m);
        p = __expf(p);
        n0 += p * x0; n1 += p * x1; deg += p;
    }
    float gat0 = n0 / (deg + 1e-16f), gat1 = n1 / (deg + 1e-16f);

    // ======== TransformerConv (ball -> ball), 4-edge pipeline ========
    u32 q2 = qP[rowD + l];
    float q0 = loF(q2), q1 = hiF(q2);
    float2 we = ((const float2*)We)[l];
    float dw = q0 * we.x + q1 * we.y;
#pragma unroll
    for (int m = 1; m <= 8; m <<= 1) dw += __shfl_xor(dw, m);
    beg = offsets[NB + d]; cnt = counts[NB + d];
    float sv0 = 0.f, sv1 = 0.f, spe = 0.f, det = 0.f;
    const uint2* kv2p = (const uint2*)kvP;
    j = 0;
    for (; j + 3 < cnt; j += 4) {
        int2 pr[4] = {pool[beg + j], pool[beg + j + 1], pool[beg + j + 2], pool[beg + j + 3]};
        uint2 kv[4];
#pragma unroll
        for (int i = 0; i < 4; i++) kv[i] = kv2p[(size_t)pr[i].x * 64 + l];
        float p[4], ea[4];
#pragma unroll
        for (int i = 0; i < 4; i++) {
            ea[i] = __int_as_float(pr[i].y);
            p[i] = q0 * loF(kv[i].x) + q1 * hiF(kv[i].x);
        }
#pragma unroll
        for (int m = 1; m <= 8; m <<= 1) {
#pragma unroll
            for (int i = 0; i < 4; i++) p[i] += __shfl_xor(p[i], m);
        }
#pragma unroll
        for (int i = 0; i < 4; i++) {
            p[i] = __expf((p[i] + ea[i] * dw) * 0.17677669529663687f);
            sv0 += p[i] * loF(kv[i].y); sv1 += p[i] * hiF(kv[i].y);
            spe += p[i] * ea[i]; det += p[i];
        }
    }
    for (; j < cnt; j++) {
        int2 pr = pool[beg + j];
        float ea = __int_as_float(pr.y);
        uint2 kv = kv2p[(size_t)pr.x * 64 + l];
        float p = q0 * loF(kv.x) + q1 * hiF(kv.x);
#pragma unroll
        for (int m = 1; m <= 8; m <<= 1) p += __shfl_xor(p, m);
        p = __expf((p + ea * dw) * 0.17677669529663687f);
        sv0 += p * loF(kv.y); sv1 += p * hiF(kv.y);
        spe += p * ea; det += p;
    }
    float tr0 = (sv0 + spe * we.x) / (det + 1e-16f);
    float tr1 = (sv1 + spe * we.y) / (det + 1e-16f);

    // ======== residual (pre-folded in skipP) + LayerNorm ========
    u32 sk = skipP[rowD + l];
    float val0 = loF(sk) + gat0 + tr0;
    float val1 = hiF(sk) + gat1 + tr1;
    float s = val0 + val1;
#pragma unroll
    for (int m = 1; m <= 32; m <<= 1) s += __shfl_xor(s, m);
    float mu = s * (1.f / 128.f);
    float d0 = val0 - mu, d1 = val1 - mu;
    float qv = d0 * d0 + d1 * d1;
#pragma unroll
    for (int m = 1; m <= 32; m <<= 1) qv += __shfl_xor(qv, m);
    float inv = rsqrtf(qv * (1.f / 128.f) + 1e-5f);
    float2 g2 = ((const float2*)ln_g)[l];
    float2 b2 = ((const float2*)ln_b)[l];
    ((float2*)out)[rowD + l] = make_float2(d0 * inv * g2.x + b2.x, d1 * inv * g2.y + b2.y);
}

// ---------------- fused ctx: xc@Wr + summ@Wl + bl + residual + LN ----------------
__global__ void ctx_fused_kernel(const float* __restrict__ xc, const float* __restrict__ summ,
                                 const float* __restrict__ Wr, const float* __restrict__ Wl,
                                 const float* __restrict__ bl,
                                 const float* __restrict__ g, const float* __restrict__ b,
                                 float* __restrict__ out) {
    __shared__ float A0[16 * 128];
    __shared__ float A1[16 * 128];
    __shared__ float CB[16 * 128];
    const int tid = threadIdx.x;
    const int row0 = blockIdx.x * 16;
    for (int i = tid; i < 16 * 128; i += 256) {
        int r = row0 + (i >> 7);
        A0[i] = (r < NC) ? xc[(size_t)r * 128 + (i & 127)] : 0.f;
        A1[i] = (r < NC) ? summ[(size_t)r * 128 + (i & 127)] : 0.f;
    }
    __syncthreads();
    const int col = tid & 127, rg = tid >> 7;
    float acc[8];
#pragma unroll
    for (int i = 0; i < 8; i++) acc[i] = 0.f;
    for (int k = 0; k < 128; k++) {
        float w0 = Wr[k * 128 + col], w1 = Wl[k * 128 + col];
#pragma unroll
        for (int i = 0; i < 8; i++)
            acc[i] += A0[(rg * 8 + i) * 128 + k] * w0 + A1[(rg * 8 + i) * 128 + k] * w1;
    }
    float bv = bl[col];
#pragma unroll
    for (int i = 0; i < 8; i++)
        CB[(rg * 8 + i) * 128 + col] = acc[i] + bv + A0[(rg * 8 + i) * 128 + col];
    __syncthreads();
    const int wv = tid >> 6, l = tid & 63;
    for (int r = 0; r < 4; r++) {
        int lr = wv * 4 + r, row = row0 + lr;
        if (row >= NC) break;
        float v0 = CB[lr * 128 + l], v1 = CB[lr * 128 + l + 64];
        float s = v0 + v1;
#pragma unroll
        for (int m = 1; m <= 32; m <<= 1) s += __shfl_xor(s, m);
        float mu = s * (1.f / 128.f);
        float d0 = v0 - mu, d1 = v1 - mu;
        float qv = d0 * d0 + d1 * d1;
#pragma unroll
        for (int m = 1; m <= 32; m <<= 1) qv += __shfl_xor(qv, m);
        float inv = rsqrtf(qv * (1.f / 128.f) + 1e-5f);
        out[(size_t)row * 128 + l] = d0 * inv * g[l] + b[l];
        out[(size_t)row * 128 + l + 64] = d1 * inv * g[l + 64] + b[l + 64];
    }
}

extern "C" void kernel_launch(void* const* d_in, const int* in_sizes, int n_in,
                              void* d_out, int out_size, void* d_ws, size_t ws_size,
                              hipStream_t stream) {
    const float* x_ball = (const float*)d_in[0];
    const float* x_player = (const float*)d_in[1];
    const float* x_context = (const float*)d_in[2];
    const int* em = (const int*)d_in[3];
    const int* ep = (const int*)d_in[4];
    const int* ei = (const int*)d_in[5];
    const float* ea_p = (const float*)d_in[6];
    const float* g_Wl = (const float*)d_in[7];
    const float* g_Wr = (const float*)d_in[8];
    const float* g_att = (const float*)d_in[9];
    const float* g_b = (const float*)d_in[10];
    const float* t_Wq = (const float*)d_in[11];
    const float* t_bq = (const float*)d_in[12];
    const float* t_Wk = (const float*)d_in[13];
    const float* t_bk = (const float*)d_in[14];
    const float* t_Wv = (const float*)d_in[15];
    const float* t_bv = (const float*)d_in[16];
    const float* t_We = (const float*)d_in[17];
    const float* t_Wskip = (const float*)d_in[18];
    const float* t_bskip = (const float*)d_in[19];
    const float* s_Wl = (const float*)d_in[20];
    const float* s_bl = (const float*)d_in[21];
    const float* s_Wr = (const float*)d_in[22];
    const float* ln_ball_g = (const float*)d_in[23];
    const float* ln_ball_b = (const float*)d_in[24];
    const float* ln_ctx_g = (const float*)d_in[25];
    const float* ln_ctx_b = (const float*)d_in[26];
    float* out = (float*)d_out;

    // ---- workspace (~85 MB) ----
    float* ws = (float*)d_ws;
    size_t o = 0;
    float* summ = ws + o;           o += (size_t)NC * 128;
    int* counts = (int*)(ws + o);   o += SEG_TOT;
    int* gbase = (int*)(ws + o);    o += 1;     // zeroed with counts
    int* offsets = (int*)(ws + o);  o += SEG_TOT;
    int* cursors = (int*)(ws + o);  o += SEG_TOT;
    if (o & 1) o++;
    int2* pool = (int2*)(ws + o);   o += (size_t)POOL_N * 2;
    ushort* Wt = (ushort*)(ws + o); o += (6 * 16384) / 2;
    u32* xlP = (u32*)(ws + o);      o += (size_t)NP * 64;
    u32* xrP = (u32*)(ws + o);      o += (size_t)NB * 64;
    u32* qP = (u32*)(ws + o);       o += (size_t)NB * 64;
    u32* skipP = (u32*)(ws + o);    o += (size_t)NB * 64;
    if (o & 1) o++;
    u32* kvP = (u32*)(ws + o);      o += (size_t)NB * 128;

    dim3 blk(256);
    hipMemsetAsync(counts, 0, (SEG_TOT + 1) * sizeof(int), stream);
    hist_wt_copy_kernel<<<FILL_BLKS + COPY_BLKS, blk, 0, stream>>>(
        em, ep, ei, counts, g_Wr, t_Wq, t_Wk, t_Wv, t_Wskip, g_Wl, Wt, x_player, out);
    scan_fused_kernel<<<NPART, blk, 0, stream>>>(counts, offsets, cursors, gbase);
    gemm6_fill_kernel<<<GEMM_BLKS + FILL_BLKS, blk, 0, stream>>>(
        x_ball, x_player, Wt, t_bq, t_bk, t_bv, t_bskip, g_b,
        xrP, qP, kvP, skipP, xlP, em, ep, ei, ea_p, cursors, pool);
    ball_sage_kernel<<<BBALL + NC, blk, 0, stream>>>(
        xlP, xrP, qP, kvP, skipP, x_ball, g_att, t_We,
        offsets, counts, pool, ln_ball_g, ln_ball_b, summ, out);
    ctx_fused_kernel<<<CTX_BLKS, blk, 0, stream>>>(x_context, summ, s_Wr, s_Wl, s_bl,
                                                   ln_ctx_g, ln_ctx_b, out + (size_t)NB * 128);
}

// Round 13
// 327.305 us; speedup vs baseline: 1.1132x; 1.0218x over previous
//
#include <hip/hip_runtime.h>
#include <hip/hip_bf16.h>

#define NB 60000
#define NP 2000
#define NC 4000
#define EM_N 150000
#define EP_N 300000
#define EI_N 150000
#define POOL_N (EM_N + EP_N + EI_N)
#define SEG_TOT (NB + NB + NC)
#define SCAN_BLK 1024
#define NPART ((SEG_TOT + SCAN_BLK - 1) / SCAN_BLK)   // 122
#define BALL_BLKS ((NB + 127) / 128)                  // 469
#define PLYR_BLKS ((NP + 127) / 128)                  // 16
#define CTXG_BLKS ((NC + 127) / 128)                  // 32
#define GEMM_BLKS (BALL_BLKS + PLYR_BLKS + CTXG_BLKS) // 517
#define FILL_BLKS ((POOL_N + 255) / 256)              // 2344
#define COPY_BLKS ((NP * 128 + 255) / 256)            // 1000
#define BBALL ((NB + 3) / 4)                          // 15000

typedef __hip_bfloat16 bf16;
typedef unsigned int u32;
typedef __attribute__((ext_vector_type(8))) short s8v;
typedef __attribute__((ext_vector_type(4))) float f4v;

__device__ __forceinline__ short f2bs(float f) {
    bf16 h = __float2bfloat16(f);
    return __builtin_bit_cast(short, h);
}
__device__ __forceinline__ float bsToF(short s) {
    return __builtin_bit_cast(float, ((unsigned)(unsigned short)s) << 16);
}
__device__ __forceinline__ float loF(u32 v) { return bsToF((short)(v & 0xffff)); }
__device__ __forceinline__ float hiF(u32 v) { return bsToF((short)(v >> 16)); }
__device__ __forceinline__ u32 packbf(float a, float b) {
    return (u32)(unsigned short)f2bs(a) | ((u32)(unsigned short)f2bs(b) << 16);
}

// ---------------- hist + 8-weight transpose + player copy ----------------
// Wt column permutation: actual col n -> store_col = (n>>5)*32 + (n&1)*16 + ((n&31)>>1)
__global__ void hist_wt_copy_kernel(const int* __restrict__ em, const int* __restrict__ ep,
                                    const int* __restrict__ ei, int* __restrict__ counts,
                                    const float* __restrict__ W0, const float* __restrict__ W1,
                                    const float* __restrict__ W2, const float* __restrict__ W3,
                                    const float* __restrict__ W4, const float* __restrict__ W5,
                                    const float* __restrict__ W6, const float* __restrict__ W7,
                                    ushort* __restrict__ Wt,
                                    const float* __restrict__ x_player, float* __restrict__ out) {
    if (blockIdx.x >= FILL_BLKS) {
        int t = (blockIdx.x - FILL_BLKS) * 256 + threadIdx.x;
        if (t < NP * 128) out[(size_t)(NB + NC) * 128 + t] = x_player[t];
        return;
    }
    int t = blockIdx.x * 256 + threadIdx.x;
    if (t < 8 * 16384) {
        int w = t >> 14, r = t & 16383, k = r >> 7, n = r & 127;
        const float* W = (w == 0) ? W0 : (w == 1) ? W1 : (w == 2) ? W2 : (w == 3) ? W3
                       : (w == 4) ? W4 : (w == 5) ? W5 : (w == 6) ? W6 : W7;
        int sc = (n >> 5) * 32 + ((n & 1) << 4) + ((n & 31) >> 1);
        Wt[w * 16384 + sc * 128 + k] = (unsigned short)f2bs(W[k * 128 + n]);
    }
    if (t < EM_N) atomicAdd(&counts[em[EM_N + t]], 1);
    else if (t < EM_N + EP_N) atomicAdd(&counts[NB + ep[EP_N + (t - EM_N)]], 1);
    else if (t < POOL_N) atomicAdd(&counts[2 * NB + ei[EI_N + (t - EM_N - EP_N)]], 1);
}

// ---------------- fused scan: block-local scan + atomic base ----------------
__global__ void scan_fused_kernel(const int* __restrict__ counts, int* __restrict__ offsets,
                                  int* __restrict__ cursors, int* __restrict__ gbase) {
    __shared__ int sd[256];
    __shared__ int sbase;
    int b = blockIdx.x, tid = threadIdx.x;
    int base = b * SCAN_BLK + tid * 4;
    int v[4]; int ts = 0;
#pragma unroll
    for (int j = 0; j < 4; j++) { int idx = base + j; v[j] = (idx < SEG_TOT) ? counts[idx] : 0; ts += v[j]; }
    sd[tid] = ts;
    for (int off = 1; off < 256; off <<= 1) {
        __syncthreads(); int t = (tid >= off) ? sd[tid - off] : 0;
        __syncthreads(); sd[tid] += t;
    }
    __syncthreads();
    if (tid == 255) sbase = atomicAdd(gbase, sd[255]);
    __syncthreads();
    int run = sd[tid] - ts + sbase;
#pragma unroll
    for (int j = 0; j < 4; j++) {
        int idx = base + j;
        if (idx < SEG_TOT) { offsets[idx] = run; cursors[idx] = run; }
        run += v[j];
    }
}

// one 128-col weight pass (4 col-tiles), optional bias + residual-from-A
__device__ __forceinline__ void mfma_pass(const s8v a[2][4], const ushort* __restrict__ wt,
                                          const float* __restrict__ bp, const float* __restrict__ Ares,
                                          int mbase, int M, int l16, int quad,
                                          u32* __restrict__ op, int stride) {
#pragma unroll
    for (int t = 0; t < 4; t++) {
        s8v blo[4], bhi[4];
#pragma unroll
        for (int kt = 0; kt < 4; kt++) {
            blo[kt] = *(const s8v*)(wt + (t * 32 + l16) * 128 + kt * 32 + quad * 8);
            bhi[kt] = *(const s8v*)(wt + (t * 32 + 16 + l16) * 128 + kt * 32 + quad * 8);
        }
        float bvlo = 0.f, bvhi = 0.f;
        if (bp) { float2 b2 = ((const float2*)bp)[t * 16 + l16]; bvlo = b2.x; bvhi = b2.y; }
#pragma unroll
        for (int mt = 0; mt < 2; mt++) {
            f4v alo = {0.f, 0.f, 0.f, 0.f}, ahi = {0.f, 0.f, 0.f, 0.f};
#pragma unroll
            for (int kt = 0; kt < 4; kt++) {
                alo = __builtin_amdgcn_mfma_f32_16x16x32_bf16(a[mt][kt], blo[kt], alo, 0, 0, 0);
                ahi = __builtin_amdgcn_mfma_f32_16x16x32_bf16(a[mt][kt], bhi[kt], ahi, 0, 0, 0);
            }
#pragma unroll
            for (int r = 0; r < 4; r++) {
                int row = mbase + mt * 16 + quad * 4 + r;
                if (row < M) {
                    float vlo = alo[r] + bvlo, vhi = ahi[r] + bvhi;
                    if (Ares) {
                        float2 xr2 = ((const float2*)Ares)[(size_t)row * 64 + t * 16 + l16];
                        vlo += xr2.x; vhi += xr2.y;
                    }
                    op[(size_t)row * stride + t * 16 + l16] = packbf(vlo, vhi);
                }
            }
        }
    }
}

// ---------------- merged: MFMA 8-weight GEMM (ball/player/ctx rows) + pool-fill ----------------
__global__ __launch_bounds__(256) void gemm6_fill_kernel(
    const float* __restrict__ Aball, const float* __restrict__ Aplyr, const float* __restrict__ Actx,
    const ushort* __restrict__ Wt,
    const float* __restrict__ bq, const float* __restrict__ bk,
    const float* __restrict__ bv_, const float* __restrict__ bskip,
    const float* __restrict__ g_b, const float* __restrict__ bl,
    u32* __restrict__ xrP, u32* __restrict__ qP, uint2* __restrict__ kvP,
    u32* __restrict__ skipP, u32* __restrict__ xlP, u32* __restrict__ xwP,
    u32* __restrict__ ctxlinP,
    const int* __restrict__ em, const int* __restrict__ ep, const int* __restrict__ ei,
    const float* __restrict__ ea_p, int* __restrict__ cursors, int2* __restrict__ pool) {
    if (blockIdx.x >= GEMM_BLKS) {
        int t = (blockIdx.x - GEMM_BLKS) * 256 + threadIdx.x;
        int seg, s; float ea = 0.f;
        if (t < EM_N) { s = em[t]; seg = em[EM_N + t]; }
        else if (t < EM_N + EP_N) { int e = t - EM_N; s = ep[e]; seg = NB + ep[EP_N + e]; ea = ea_p[e]; }
        else if (t < POOL_N) { int e = t - EM_N - EP_N; s = ei[e]; seg = 2 * NB + ei[EI_N + e]; }
        else return;
        int pos = atomicAdd(&cursors[seg], 1);
        pool[pos] = make_int2(s, __float_as_int(ea));
        return;
    }
    const int lane = threadIdx.x & 63;
    const int wv = threadIdx.x >> 6;
    const int quad = lane >> 4, l16 = lane & 15;
    int kind, bidx;   // 0=ball 1=player 2=ctx
    if (blockIdx.x < BALL_BLKS) { kind = 0; bidx = blockIdx.x; }
    else if (blockIdx.x < BALL_BLKS + PLYR_BLKS) { kind = 1; bidx = blockIdx.x - BALL_BLKS; }
    else { kind = 2; bidx = blockIdx.x - BALL_BLKS - PLYR_BLKS; }
    const int M = (kind == 0) ? NB : (kind == 1) ? NP : NC;
    const float* A = (kind == 0) ? Aball : (kind == 1) ? Aplyr : Actx;
    const int mbase = bidx * 128 + wv * 32;

    s8v a[2][4];
#pragma unroll
    for (int mt = 0; mt < 2; mt++) {
        int row = mbase + mt * 16 + l16;
        if (row >= M) row = M - 1;
        const float* ap = A + (size_t)row * 128 + quad * 8;
#pragma unroll
        for (int kt = 0; kt < 4; kt++) {
            const float4* p = (const float4*)(ap + kt * 32);
            float4 u = p[0], v = p[1];
            s8v f;
            f[0] = f2bs(u.x); f[1] = f2bs(u.y); f[2] = f2bs(u.z); f[3] = f2bs(u.w);
            f[4] = f2bs(v.x); f[5] = f2bs(v.y); f[6] = f2bs(v.z); f[7] = f2bs(v.w);
            a[mt][kt] = f;
        }
    }

    if (kind == 1) {   // player: xl
        mfma_pass(a, Wt + 5 * 16384, nullptr, nullptr, mbase, M, l16, quad, xlP, 64);
        return;
    }
    if (kind == 2) {   // ctx: ctxlin = xc@s_Wr + bl + xc
        mfma_pass(a, Wt + 7 * 16384, bl, Actx, mbase, M, l16, quad, ctxlinP, 64);
        return;
    }
    // ball: xr, q, kv(joint), skip(+resid), xw
    mfma_pass(a, Wt + 0 * 16384, nullptr, nullptr, mbase, M, l16, quad, xrP, 64);
    mfma_pass(a, Wt + 1 * 16384, bq, nullptr, mbase, M, l16, quad, qP, 64);
    // ---- joint kv ----
    {
        const ushort* wtk = Wt + 2 * 16384;
        const ushort* wtv = Wt + 3 * 16384;
#pragma unroll
        for (int t = 0; t < 4; t++) {
            float2 bk2 = ((const float2*)bk)[t * 16 + l16];
            float2 bv2 = ((const float2*)bv_)[t * 16 + l16];
            u32 kpk[2][4];
            {
                s8v blo[4], bhi[4];
#pragma unroll
                for (int kt = 0; kt < 4; kt++) {
                    blo[kt] = *(const s8v*)(wtk + (t * 32 + l16) * 128 + kt * 32 + quad * 8);
                    bhi[kt] = *(const s8v*)(wtk + (t * 32 + 16 + l16) * 128 + kt * 32 + quad * 8);
                }
#pragma unroll
                for (int mt = 0; mt < 2; mt++) {
                    f4v alo = {0.f, 0.f, 0.f, 0.f}, ahi = {0.f, 0.f, 0.f, 0.f};
#pragma unroll
                    for (int kt = 0; kt < 4; kt++) {
                        alo = __builtin_amdgcn_mfma_f32_16x16x32_bf16(a[mt][kt], blo[kt], alo, 0, 0, 0);
                        ahi = __builtin_amdgcn_mfma_f32_16x16x32_bf16(a[mt][kt], bhi[kt], ahi, 0, 0, 0);
                    }
#pragma unroll
                    for (int r = 0; r < 4; r++)
                        kpk[mt][r] = packbf(alo[r] + bk2.x, ahi[r] + bk2.y);
                }
            }
            {
                s8v blo[4], bhi[4];
#pragma unroll
                for (int kt = 0; kt < 4; kt++) {
                    blo[kt] = *(const s8v*)(wtv + (t * 32 + l16) * 128 + kt * 32 + quad * 8);
                    bhi[kt] = *(const s8v*)(wtv + (t * 32 + 16 + l16) * 128 + kt * 32 + quad * 8);
                }
#pragma unroll
                for (int mt = 0; mt < 2; mt++) {
                    f4v alo = {0.f, 0.f, 0.f, 0.f}, ahi = {0.f, 0.f, 0.f, 0.f};
#pragma unroll
                    for (int kt = 0; kt < 4; kt++) {
                        alo = __builtin_amdgcn_mfma_f32_16x16x32_bf16(a[mt][kt], blo[kt], alo, 0, 0, 0);
                        ahi = __builtin_amdgcn_mfma_f32_16x16x32_bf16(a[mt][kt], bhi[kt], ahi, 0, 0, 0);
                    }
#pragma unroll
                    for (int r = 0; r < 4; r++) {
                        int row = mbase + mt * 16 + quad * 4 + r;
                        if (row < NB)
                            kvP[(size_t)row * 64 + t * 16 + l16] =
                                make_uint2(kpk[mt][r], packbf(alo[r] + bv2.x, ahi[r] + bv2.y));
                    }
                }
            }
        }
    }
    mfma_pass(a, Wt + 4 * 16384, bskip, Aball, mbase, M, l16, quad, skipP, 64);   // g_b folded below
    // NOTE: g_b is added via bias trick: skip pass uses bskip only; add g_b separately:
    // (folded into bskip at launch is not possible — do it here via second bias read)
    mfma_pass(a, Wt + 6 * 16384, nullptr, nullptr, mbase, M, l16, quad, xwP, 64);
}

// g_b add-on for skipP (tiny: 60000*64 u32): fold into ball kernel read instead.

// ---------------- merged: ball (GAT+TR+skip+LN) | ctx (sage on xw + ctxlin + LN) ----------------
__global__ __launch_bounds__(256) void ball_sage_kernel(
    const u32* __restrict__ xlP, const u32* __restrict__ xrP, const u32* __restrict__ qP,
    const uint2* __restrict__ kvP, const u32* __restrict__ skipP, const u32* __restrict__ xwP,
    const u32* __restrict__ ctxlinP,
    const float* __restrict__ g_att, const float* __restrict__ g_b, const float* __restrict__ We,
    const int* __restrict__ offsets, const int* __restrict__ counts,
    const int2* __restrict__ pool,
    const float* __restrict__ ln_g, const float* __restrict__ ln_b,
    const float* __restrict__ cg, const float* __restrict__ cb,
    float* __restrict__ out) {
    __shared__ float part[4][128];
    const int wv = threadIdx.x >> 6, l = threadIdx.x & 63;

    if (blockIdx.x >= BBALL) {
        // ---- ctx: gather-mean xw + ctxlin + LN ----
        int c = blockIdx.x - BBALL;
        int beg = offsets[2 * NB + c], cnt = counts[2 * NB + c];
        float s0 = 0.f, s1 = 0.f;
        for (int j = wv; j < cnt; j += 4) {
            u32 xv = xwP[(size_t)pool[beg + j].x * 64 + l];
            s0 += loF(xv); s1 += hiF(xv);
        }
        part[wv][l * 2] = s0; part[wv][l * 2 + 1] = s1;
        __syncthreads();
        if (wv == 0) {
            float m = fmaxf((float)cnt, 1.f);
            u32 cl = ctxlinP[(size_t)c * 64 + l];
            float v0 = (part[0][l * 2] + part[1][l * 2] + part[2][l * 2] + part[3][l * 2]) / m + loF(cl);
            float v1 = (part[0][l * 2 + 1] + part[1][l * 2 + 1] + part[2][l * 2 + 1] + part[3][l * 2 + 1]) / m + hiF(cl);
            float s = v0 + v1;
#pragma unroll
            for (int m2 = 1; m2 <= 32; m2 <<= 1) s += __shfl_xor(s, m2);
            float mu = s * (1.f / 128.f);
            float d0 = v0 - mu, d1 = v1 - mu;
            float qv = d0 * d0 + d1 * d1;
#pragma unroll
            for (int m2 = 1; m2 <= 32; m2 <<= 1) qv += __shfl_xor(qv, m2);
            float inv = rsqrtf(qv * (1.f / 128.f) + 1e-5f);
            float2 g2 = ((const float2*)cg)[l];
            float2 b2 = ((const float2*)cb)[l];
            ((float2*)out)[(size_t)(NB + c) * 64 + l] =
                make_float2(d0 * inv * g2.x + b2.x, d1 * inv * g2.y + b2.y);
        }
        return;
    }

    // ---- ball path: one wave per node, pairing (2l,2l+1), head = l>>4 ----
    const int d = blockIdx.x * 4 + wv;
    const size_t rowD = (size_t)d * 64;

    // ======== GATv2, padded 4-edge batches ========
    float2 att = ((const float2*)g_att)[l];
    u32 xr2 = xrP[rowD + l];
    float xr0 = loF(xr2), xr1 = hiF(xr2);
    int beg = offsets[d], cnt = counts[d];
    float n0 = 0.f, n1 = 0.f, deg = 0.f;
    for (int j = 0; j < cnt; j += 4) {
        int sI[4]; bool ok[4];
#pragma unroll
        for (int i = 0; i < 4; i++) {
            ok[i] = (j + i < cnt);
            sI[i] = ok[i] ? pool[beg + j + i].x : 0;
        }
        u32 xv[4];
#pragma unroll
        for (int i = 0; i < 4; i++) xv[i] = xlP[(size_t)sI[i] * 64 + l];
        float p[4], xa[4], xb[4];
#pragma unroll
        for (int i = 0; i < 4; i++) {
            xa[i] = loF(xv[i]); xb[i] = hiF(xv[i]);
            float u0 = xa[i] + xr0; u0 = u0 > 0.f ? u0 : 0.2f * u0;
            float u1 = xb[i] + xr1; u1 = u1 > 0.f ? u1 : 0.2f * u1;
            p[i] = u0 * att.x + u1 * att.y;
        }
#pragma unroll
        for (int m = 1; m <= 8; m <<= 1) {
#pragma unroll
            for (int i = 0; i < 4; i++) p[i] += __shfl_xor(p[i], m);
        }
#pragma unroll
        for (int i = 0; i < 4; i++) {
            p[i] = ok[i] ? __expf(p[i]) : 0.f;
            n0 += p[i] * xa[i]; n1 += p[i] * xb[i]; deg += p[i];
        }
    }
    float gat0 = n0 / (deg + 1e-16f), gat1 = n1 / (deg + 1e-16f);

    // ======== TransformerConv, padded 4-edge batches ========
    u32 q2 = qP[rowD + l];
    float q0 = loF(q2), q1 = hiF(q2);
    float2 we = ((const float2*)We)[l];
    float dw = q0 * we.x + q1 * we.y;
#pragma unroll
    for (int m = 1; m <= 8; m <<= 1) dw += __shfl_xor(dw, m);
    beg = offsets[NB + d]; cnt = counts[NB + d];
    float sv0 = 0.f, sv1 = 0.f, spe = 0.f, det = 0.f;
    for (int j = 0; j < cnt; j += 4) {
        int2 pr[4]; bool ok[4];
#pragma unroll
        for (int i = 0; i < 4; i++) {
            ok[i] = (j + i < cnt);
            pr[i] = ok[i] ? pool[beg + j + i] : make_int2(0, 0);
        }
        uint2 kv[4];
#pragma unroll
        for (int i = 0; i < 4; i++) kv[i] = kvP[(size_t)pr[i].x * 64 + l];
        float p[4], ea[4];
#pragma unroll
        for (int i = 0; i < 4; i++) {
            ea[i] = __int_as_float(pr[i].y);
            p[i] = q0 * loF(kv[i].x) + q1 * hiF(kv[i].x);
        }
#pragma unroll
        for (int m = 1; m <= 8; m <<= 1) {
#pragma unroll
            for (int i = 0; i < 4; i++) p[i] += __shfl_xor(p[i], m);
        }
#pragma unroll
        for (int i = 0; i < 4; i++) {
            p[i] = ok[i] ? __expf((p[i] + ea[i] * dw) * 0.17677669529663687f) : 0.f;
            sv0 += p[i] * loF(kv[i].y); sv1 += p[i] * hiF(kv[i].y);
            spe += p[i] * ea[i]; det += p[i];
        }
    }
    float tr0 = (sv0 + spe * we.x) / (det + 1e-16f);
    float tr1 = (sv1 + spe * we.y) / (det + 1e-16f);

    // ======== residual(skipP has x_ball+bskip; add g_b here) + LayerNorm ========
    u32 sk = skipP[rowD + l];
    float2 gb2 = ((const float2*)g_b)[l];
    float val0 = loF(sk) + gb2.x + gat0 + tr0;
    float val1 = hiF(sk) + gb2.y + gat1 + tr1;
    float s = val0 + val1;
#pragma unroll
    for (int m = 1; m <= 32; m <<= 1) s += __shfl_xor(s, m);
    float mu = s * (1.f / 128.f);
    float d0 = val0 - mu, d1 = val1 - mu;
    float qv = d0 * d0 + d1 * d1;
#pragma unroll
    for (int m = 1; m <= 32; m <<= 1) qv += __shfl_xor(qv, m);
    float inv = rsqrtf(qv * (1.f / 128.f) + 1e-5f);
    float2 g2 = ((const float2*)ln_g)[l];
    float2 b2 = ((const float2*)ln_b)[l];
    ((float2*)out)[rowD + l] = make_float2(d0 * inv * g2.x + b2.x, d1 * inv * g2.y + b2.y);
}

extern "C" void kernel_launch(void* const* d_in, const int* in_sizes, int n_in,
                              void* d_out, int out_size, void* d_ws, size_t ws_size,
                              hipStream_t stream) {
    const float* x_ball = (const float*)d_in[0];
    const float* x_player = (const float*)d_in[1];
    const float* x_context = (const float*)d_in[2];
    const int* em = (const int*)d_in[3];
    const int* ep = (const int*)d_in[4];
    const int* ei = (const int*)d_in[5];
    const float* ea_p = (const float*)d_in[6];
    const float* g_Wl = (const float*)d_in[7];
    const float* g_Wr = (const float*)d_in[8];
    const float* g_att = (const float*)d_in[9];
    const float* g_b = (const float*)d_in[10];
    const float* t_Wq = (const float*)d_in[11];
    const float* t_bq = (const float*)d_in[12];
    const float* t_Wk = (const float*)d_in[13];
    const float* t_bk = (const float*)d_in[14];
    const float* t_Wv = (const float*)d_in[15];
    const float* t_bv = (const float*)d_in[16];
    const float* t_We = (const float*)d_in[17];
    const float* t_Wskip = (const float*)d_in[18];
    const float* t_bskip = (const float*)d_in[19];
    const float* s_Wl = (const float*)d_in[20];
    const float* s_bl = (const float*)d_in[21];
    const float* s_Wr = (const float*)d_in[22];
    const float* ln_ball_g = (const float*)d_in[23];
    const float* ln_ball_b = (const float*)d_in[24];
    const float* ln_ctx_g = (const float*)d_in[25];
    const float* ln_ctx_b = (const float*)d_in[26];
    float* out = (float*)d_out;

    // ---- workspace ----
    float* ws = (float*)d_ws;
    size_t o = 0;
    int* counts = (int*)(ws + o);   o += SEG_TOT;
    int* gbase = (int*)(ws + o);    o += 1;     // zeroed with counts
    int* offsets = (int*)(ws + o);  o += SEG_TOT;
    int* cursors = (int*)(ws + o);  o += SEG_TOT;
    if (o & 1) o++;
    int2* pool = (int2*)(ws + o);   o += (size_t)POOL_N * 2;
    ushort* Wt = (ushort*)(ws + o); o += (8 * 16384) / 2;
    u32* xlP = (u32*)(ws + o);      o += (size_t)NP * 64;
    u32* xrP = (u32*)(ws + o);      o += (size_t)NB * 64;
    u32* qP = (u32*)(ws + o);       o += (size_t)NB * 64;
    u32* skipP = (u32*)(ws + o);    o += (size_t)NB * 64;
    u32* xwP = (u32*)(ws + o);      o += (size_t)NB * 64;
    u32* ctxlinP = (u32*)(ws + o);  o += (size_t)NC * 64;
    if (o & 1) o++;
    uint2* kvP = (uint2*)(ws + o);  o += (size_t)NB * 128;

    dim3 blk(256);
    hipMemsetAsync(counts, 0, (SEG_TOT + 1) * sizeof(int), stream);
    hist_wt_copy_kernel<<<FILL_BLKS + COPY_BLKS, blk, 0, stream>>>(
        em, ep, ei, counts, g_Wr, t_Wq, t_Wk, t_Wv, t_Wskip, g_Wl, s_Wl, s_Wr, Wt, x_player, out);
    scan_fused_kernel<<<NPART, blk, 0, stream>>>(counts, offsets, cursors, gbase);
    gemm6_fill_kernel<<<GEMM_BLKS + FILL_BLKS, blk, 0, stream>>>(
        x_ball, x_player, x_context, Wt, t_bq, t_bk, t_bv, t_bskip, g_b, s_bl,
        xrP, qP, kvP, skipP, xlP, xwP, ctxlinP, em, ep, ei, ea_p, cursors, pool);
    ball_sage_kernel<<<BBALL + NC, blk, 0, stream>>>(
        xlP, xrP, qP, kvP, skipP, xwP, ctxlinP, g_att, g_b, t_We,
        offsets, counts, pool, ln_ball_g, ln_ball_b, ln_ctx_g, ln_ctx_b, out);
}